// Round 7
// baseline (5191.123 us; speedup 1.0000x reference)
//
#include <hip/hip_runtime.h>
#include <hip/hip_bf16.h>

typedef unsigned short u16;
typedef unsigned int u32;
typedef unsigned long long u64;

#define HD 512
#define BATCH 128
#define TENC 512
#define WPAD 520   // LDS row stride in bf16 elems (even -> u32-aligned rows)

typedef float f32x4 __attribute__((ext_vector_type(4)));
typedef short s16x8 __attribute__((ext_vector_type(8)));

__device__ __forceinline__ u16 f2b(float f) {
    u32 u = __float_as_uint(f);
    u32 r = (u + 0x7FFFu + ((u >> 16) & 1u)) >> 16;   // RNE
    return (u16)r;
}
__device__ __forceinline__ float b2f(u16 h) {
    return __uint_as_float(((u32)h) << 16);
}
__device__ __forceinline__ float sigm(float z) { return 1.0f / (1.0f + __expf(-z)); }
__device__ __forceinline__ float tanh_f(float z) { return 1.0f - 2.0f / (__expf(2.0f * z) + 1.0f); }

// ---------------------------------------------------------------------------
// init: seed tagged h-buffer. Layout: hb64[(g*2+parity)*4096 + b*256 + jp]
//   word = (bf16 h[2jp] | bf16 h[2jp+1]<<16) | ((u64)tag << 32)
// parity0 holds h_0 with tag 0; parity1 zeroed (tag 0, never matches t>=1).
// Also build rnn_Whh transposed bf16 [k][j] for coalesced decoder reads.
// ---------------------------------------------------------------------------
__global__ void init_misc(const float* __restrict__ h0, const float* __restrict__ rWhh,
                          u64* __restrict__ hb64, u16* __restrict__ rT) {
    int idx = blockIdx.x * 256 + threadIdx.x;      // 512 blocks x 256 = 131072
    if (idx < 65536) {                              // 8 g x 2 parity x 4096 words
        int g   = idx >> 13;
        int r   = idx & 8191;
        int p   = r >> 12;
        int ofs = r & 4095;
        int b   = ofs >> 8, jp = ofs & 255;
        u64 v = 0ull;                               // tag 0
        if (p == 0) {
            const float* hrow = h0 + (size_t)(g * 16 + b) * HD + jp * 2;
            u32 lo = (u32)f2b(hrow[0]) | ((u32)f2b(hrow[1]) << 16);
            v = (u64)lo;                            // tag 0 for h_0
        }
        hb64[(size_t)(g * 2 + p) * 4096 + b * 256 + jp] = v;
    }
    for (int i = idx; i < 262144; i += 131072) {    // rT[k*512+j] = rWhh[j][k]
        int k = i >> 9, j = i & 511;
        rT[i] = f2b(rWhh[j * 512 + k]);
    }
}

// ---------------------------------------------------------------------------
// Encoder LSTM, 4-GROUP INTERLEAVE: 32 wgs; wg = (sl, quad). Each wg runs
// slot sl of FOUR independent batch-groups, round-robin per timestep. The
// per-group handoff protocol is the round-1 proven one (tagged 8B agent
// words, parity-2). All 4 tag-volleys are issued at iteration top; group X's
// tags were stored >=3 phases earlier, so its volley returns valid and the
// MALL round-trip hides under the other groups' compute. Whh fragments (bw)
// depend only on sl -> shared across groups. hlds/exg reused across phases
// (barrier-separated). Deadlock-free: fixed program order, unbounded-poll
// fallback identical to round-1.
// ---------------------------------------------------------------------------
#define PROC(GI, VV, SRC, XV)                                                 \
    do {                                                                      \
        for (;;) {                                                            \
            bool ok = true;                                                   \
            _Pragma("unroll")                                                 \
            for (int i = 0; i < 8; ++i) {                                     \
                if ((u32)(VV[i] >> 32) != want) {                             \
                    ok = false;                                               \
                    VV[i] = __hip_atomic_load(SRC + tid + i * 512,            \
                                __ATOMIC_RELAXED, __HIP_MEMORY_SCOPE_AGENT);  \
                }                                                             \
            }                                                                 \
            if (ok) break;                                                    \
        }                                                                     \
        _Pragma("unroll")                                                     \
        for (int i = 0; i < 8; ++i) {                                         \
            int idx = tid + i * 512;                                          \
            hlds32[(idx >> 8) * 260 + (idx & 255)] = (u32)VV[i];              \
        }                                                                     \
        __syncthreads();  /* S1: hlds ready */                                \
        f32x4 acc0 = {0.f, 0.f, 0.f, 0.f}, acc1 = {0.f, 0.f, 0.f, 0.f};       \
        _Pragma("unroll")                                                     \
        for (int ks = 0; ks < 16; ks += 2) {                                  \
            s16x8 av0 = *(const s16x8*)&hlds[cl * WPAD + ks * 32 + q * 8];    \
            s16x8 av1 = *(const s16x8*)&hlds[cl * WPAD + (ks + 1) * 32 + q * 8]; \
            acc0 = __builtin_amdgcn_mfma_f32_16x16x32_bf16(av0, bw[ks], acc0, 0, 0, 0); \
            acc1 = __builtin_amdgcn_mfma_f32_16x16x32_bf16(av1, bw[ks + 1], acc1, 0, 0, 0); \
        }                                                                     \
        f32x4 accs = acc0 + acc1;                                             \
        _Pragma("unroll")                                                     \
        for (int r4 = 0; r4 < 4; ++r4)                                        \
            exg[(q * 4 + r4) * 132 + R + cl] = accs[r4];                      \
        __syncthreads();  /* S2: exg ready + hlds reads done */               \
        {                                                                     \
            const float* exb = &exg[bT * 132];                                \
            float ga = exb[jl]      + XV * wih_l[jl]      + bias_l[jl];       \
            float gf = exb[32 + jl] + XV * wih_l[32 + jl] + bias_l[32 + jl];  \
            float gg = exb[64 + jl] + XV * wih_l[64 + jl] + bias_l[64 + jl];  \
            float go = exb[96 + jl] + XV * wih_l[96 + jl] + bias_l[96 + jl];  \
            float cc = sigm(gf) * cst[GI] + sigm(ga) * tanh_f(gg);            \
            cst[GI] = cc;                                                     \
            float hv = sigm(go) * tanh_f(cc);                                 \
            u16 h16 = f2b(hv);                                                \
            u32 me = (u32)h16;                                                \
            u32 up = (u32)__shfl_down((int)me, 1, 64);                        \
            if ((jl & 1) == 0) {                                              \
                u64 word = (u64)(me | (up << 16)) | ((u64)(u32)(t + 1) << 32);\
                u64* dst = hb64 + (size_t)((p4 + GI) * 2 + ((t + 1) & 1)) * 4096 \
                                + bT * 256 + (jgl >> 1);                      \
                __hip_atomic_store(dst, word, __ATOMIC_RELAXED,               \
                                   __HIP_MEMORY_SCOPE_AGENT);                 \
            }                                                                 \
            enc[((size_t)t * BATCH + (p4 + GI) * 16 + bT) * HD + jgl] = h16;  \
        }                                                                     \
    } while (0)

__global__ __launch_bounds__(512, 1) void enc_lstm(
    const float* __restrict__ xseq, const float* __restrict__ c0,
    const float* __restrict__ Wih, const float* __restrict__ Whh,
    const float* __restrict__ bih, const float* __restrict__ bhh,
    u16* __restrict__ enc, u64* __restrict__ hb64) {

    __shared__ u16 hlds[16 * WPAD];     // 16640 B: staged h tile (reused x4)
    __shared__ float exg[16 * 132];     // 8448 B: gate pre-activations (reused x4)
    __shared__ float bias_l[128];
    __shared__ float wih_l[128];

    const int tid = threadIdx.x;
    const int sl = blockIdx.x & 15;     // hidden slot 0..15
    const int p4 = (blockIdx.x >> 4) * 4;   // first group of this wg's quad

    if (tid < 128) {
        int n = (tid >> 5) * 512 + sl * 32 + (tid & 31);
        bias_l[tid] = bih[n] + bhh[n];
        wih_l[tid] = Wih[n];
    }

    const int bT = tid >> 5, jl = tid & 31;               // cell-update mapping
    float cst[4];
    #pragma unroll
    for (int gi = 0; gi < 4; ++gi)
        cst[gi] = c0[((p4 + gi) * 16 + bT) * HD + sl * 32 + jl];

    const int lane = tid & 63, wv = tid >> 6;
    const int q = lane >> 4, cl = lane & 15;
    const int R = (wv >> 1) * 32 + (wv & 1) * 16;         // wave's 16 gate-rows

    // hoist this lane's 16 B-fragments of Whh into registers (64 VGPRs) --
    // depends only on sl, SHARED by all 4 groups.
    s16x8 bw[16];
    {
        int r = R + cl;
        int grow = (r >> 5) * 512 + sl * 32 + (r & 31);
        const float* wrow = Whh + (size_t)grow * 512;
        #pragma unroll
        for (int ks = 0; ks < 16; ++ks) {
            s16x8 v;
            #pragma unroll
            for (int j = 0; j < 8; ++j)
                v[j] = (short)f2b(wrow[ks * 32 + q * 8 + j]);
            bw[ks] = v;
        }
    }

    u32* hlds32 = (u32*)hlds;
    __syncthreads();

    const int jgl = sl * 32 + jl;

    for (int t = 0; t < TENC; ++t) {
        const u32 want = (u32)t;
        const u64* s0 = hb64 + (size_t)((p4 + 0) * 2 + (t & 1)) * 4096;
        const u64* s1 = hb64 + (size_t)((p4 + 1) * 2 + (t & 1)) * 4096;
        const u64* s2 = hb64 + (size_t)((p4 + 2) * 2 + (t & 1)) * 4096;
        const u64* s3 = hb64 + (size_t)((p4 + 3) * 2 + (t & 1)) * 4096;

        // issue ALL 4 volleys up front: 32 independent loads in flight.
        u64 vv0[8], vv1[8], vv2[8], vv3[8];
        #pragma unroll
        for (int i = 0; i < 8; ++i)
            vv0[i] = __hip_atomic_load(s0 + tid + i * 512, __ATOMIC_RELAXED,
                                       __HIP_MEMORY_SCOPE_AGENT);
        #pragma unroll
        for (int i = 0; i < 8; ++i)
            vv1[i] = __hip_atomic_load(s1 + tid + i * 512, __ATOMIC_RELAXED,
                                       __HIP_MEMORY_SCOPE_AGENT);
        #pragma unroll
        for (int i = 0; i < 8; ++i)
            vv2[i] = __hip_atomic_load(s2 + tid + i * 512, __ATOMIC_RELAXED,
                                       __HIP_MEMORY_SCOPE_AGENT);
        #pragma unroll
        for (int i = 0; i < 8; ++i)
            vv3[i] = __hip_atomic_load(s3 + tid + i * 512, __ATOMIC_RELAXED,
                                       __HIP_MEMORY_SCOPE_AGENT);

        float xv0 = xseq[t * BATCH + (p4 + 0) * 16 + bT];
        float xv1 = xseq[t * BATCH + (p4 + 1) * 16 + bT];
        float xv2 = xseq[t * BATCH + (p4 + 2) * 16 + bT];
        float xv3 = xseq[t * BATCH + (p4 + 3) * 16 + bT];

        PROC(0, vv0, s0, xv0);
        PROC(1, vv1, s1, xv1);
        PROC(2, vv2, s2, xv2);
        PROC(3, vv3, s3, xv3);
    }
}

// ---------------------------------------------------------------------------
// Fused decoder (round-6 proven): one wg per batch row, 32 steps; p2 does
// 8 t per iteration (batched butterflies, one rescale per 8-t block).
// ---------------------------------------------------------------------------
__global__ __launch_bounds__(512, 1) void dec_all(
    const float* __restrict__ xlast, const u16* __restrict__ enc,
    const u16* __restrict__ rT, const float* __restrict__ rWih,
    const float* __restrict__ rbih, const float* __restrict__ rbhh,
    const float* __restrict__ linW, const float* __restrict__ linb,
    float* __restrict__ dout) {

    __shared__ float hp[512];          // h entering the step
    __shared__ float ctxl[8 * 512];    // p1 partials, then p2 ctx partials
    __shared__ float red[512];         // hn broadcast, then reduce slots
    __shared__ float mw[8], lw[8];
    __shared__ float xsh;

    const int tid = threadIdx.x;
    const int b = blockIdx.x;
    const int wv = tid >> 6, lane = tid & 63;

    hp[tid] = b2f(enc[(size_t)511 * BATCH * HD + b * HD + tid]);  // h_enc
    float x = xlast[b];
    const float bia = rbih[tid] + rbhh[tid];
    const float wih = rWih[tid];
    const float lwt = linW[tid];
    const float lb = linb[0];
    const uint4* rT4 = (const uint4*)rT;                 // [512 k][64 chunks]
    const u16* ebase = enc + (size_t)b * HD + lane * 8;  // t-stride = 65536 elems
    __syncthreads();

    for (int s = 0; s < 32; ++s) {
        // ---- phase 1: wave wv covers k in [wv*64, wv*64+64)
        float pa[8] = {0, 0, 0, 0, 0, 0, 0, 0};
        const uint4* base = rT4 + (size_t)(wv * 64) * 64 + lane;
        #pragma unroll 4
        for (int kk = 0; kk < 64; ++kk) {
            float hk = hp[wv * 64 + kk];
            uint4 w = base[kk * 64];
            pa[0] = fmaf(hk, b2f((u16)(w.x & 0xFFFF)), pa[0]);
            pa[1] = fmaf(hk, b2f((u16)(w.x >> 16)),    pa[1]);
            pa[2] = fmaf(hk, b2f((u16)(w.y & 0xFFFF)), pa[2]);
            pa[3] = fmaf(hk, b2f((u16)(w.y >> 16)),    pa[3]);
            pa[4] = fmaf(hk, b2f((u16)(w.z & 0xFFFF)), pa[4]);
            pa[5] = fmaf(hk, b2f((u16)(w.z >> 16)),    pa[5]);
            pa[6] = fmaf(hk, b2f((u16)(w.w & 0xFFFF)), pa[6]);
            pa[7] = fmaf(hk, b2f((u16)(w.w >> 16)),    pa[7]);
        }
        #pragma unroll
        for (int i = 0; i < 8; ++i) ctxl[wv * 512 + lane * 8 + i] = pa[i];
        __syncthreads();

        float a = bia + x * wih;
        #pragma unroll
        for (int i = 0; i < 8; ++i) a += ctxl[i * 512 + tid];
        float hv = tanh_f(a);
        red[tid] = hv;                  // hn broadcast
        __syncthreads();

        // ---- phase 2: wave wv handles t = it*64 + i*8 + wv, 8 t per iter
        float h8[8];
        #pragma unroll
        for (int i = 0; i < 8; ++i) h8[i] = red[lane * 8 + i];
        float m = -1e30f, l = 0.f;
        float acc[8] = {0, 0, 0, 0, 0, 0, 0, 0};

        uint4 buf[8];
        #pragma unroll
        for (int i = 0; i < 8; ++i)
            buf[i] = *(const uint4*)(ebase + (size_t)(i * 8 + wv) * 65536);

        for (int it = 0; it < 8; ++it) {
            uint4 nxt[8];
            if (it < 7) {
                #pragma unroll
                for (int i = 0; i < 8; ++i)
                    nxt[i] = *(const uint4*)(ebase +
                               (size_t)((it + 1) * 64 + i * 8 + wv) * 65536);
            }
            float e[8][8], sp[8];
            #pragma unroll
            for (int i = 0; i < 8; ++i) {
                uint4 ev = buf[i];
                e[i][0] = b2f((u16)(ev.x & 0xFFFF)); e[i][1] = b2f((u16)(ev.x >> 16));
                e[i][2] = b2f((u16)(ev.y & 0xFFFF)); e[i][3] = b2f((u16)(ev.y >> 16));
                e[i][4] = b2f((u16)(ev.z & 0xFFFF)); e[i][5] = b2f((u16)(ev.z >> 16));
                e[i][6] = b2f((u16)(ev.w & 0xFFFF)); e[i][7] = b2f((u16)(ev.w >> 16));
                float sd = 0.f;
                #pragma unroll
                for (int j = 0; j < 8; ++j) sd = fmaf(e[i][j], h8[j], sd);
                sp[i] = sd;
            }
            // batched butterfly: 6 dependent stages, 8-way ILP
            #pragma unroll
            for (int mk = 1; mk < 64; mk <<= 1) {
                #pragma unroll
                for (int i = 0; i < 8; ++i) sp[i] += __shfl_xor(sp[i], mk, 64);
            }
            float pm = sp[0];
            #pragma unroll
            for (int i = 1; i < 8; ++i) pm = fmaxf(pm, sp[i]);
            if (pm > m) {                           // one rescale per 8-t block
                float sc = __expf(m - pm);
                l *= sc;
                #pragma unroll
                for (int j = 0; j < 8; ++j) acc[j] *= sc;
                m = pm;
            }
            #pragma unroll
            for (int i = 0; i < 8; ++i) {
                float p = __expf(sp[i] - m);
                l += p;
                #pragma unroll
                for (int j = 0; j < 8; ++j) acc[j] = fmaf(p, e[i][j], acc[j]);
            }
            if (it < 7) {
                #pragma unroll
                for (int i = 0; i < 8; ++i) buf[i] = nxt[i];
            }
        }
        if (lane == 0) { mw[wv] = m; lw[wv] = l; }
        #pragma unroll
        for (int i = 0; i < 8; ++i) ctxl[wv * HD + lane * 8 + i] = acc[i];
        __syncthreads();

        // ---- phase 3: merge online-softmax states, project, relu
        float M = mw[0];
        #pragma unroll
        for (int i = 1; i < 8; ++i) M = fmaxf(M, mw[i]);
        float L = 0.f, aw[8];
        #pragma unroll
        for (int i = 0; i < 8; ++i) { aw[i] = __expf(mw[i] - M); L += aw[i] * lw[i]; }
        float cj = 0.f;
        #pragma unroll
        for (int i = 0; i < 8; ++i) cj = fmaf(aw[i], ctxl[i * HD + tid], cj);
        float r = cj * lwt;
        #pragma unroll
        for (int mk = 1; mk < 64; mk <<= 1) r += __shfl_xor(r, mk, 64);
        if (lane == 0) red[wv] = r;
        __syncthreads();
        if (tid == 0) {
            float o = (red[0] + red[1] + red[2] + red[3] +
                       red[4] + red[5] + red[6] + red[7]) / L + lb;
            o = fmaxf(o, 0.f);
            dout[s * BATCH + b] = o;
            xsh = o;
        }
        __syncthreads();
        x = xsh;
        hp[tid] = hv;                   // h for next step
        __syncthreads();
    }
}

// ---------------------------------------------------------------------------
extern "C" void kernel_launch(void* const* d_in, const int* in_sizes, int n_in,
                              void* d_out, int out_size, void* d_ws, size_t ws_size,
                              hipStream_t stream) {
    const float* xseq = (const float*)d_in[0];   // [513,128,1]
    const float* h0   = (const float*)d_in[1];
    const float* c0   = (const float*)d_in[2];
    const float* Wih  = (const float*)d_in[3];   // [2048,1]
    const float* Whh  = (const float*)d_in[4];   // [2048,512]
    const float* bih  = (const float*)d_in[5];
    const float* bhh  = (const float*)d_in[6];
    const float* rWih = (const float*)d_in[7];   // [512,1]
    const float* rWhh = (const float*)d_in[8];   // [512,512]
    const float* rbih = (const float*)d_in[9];
    const float* rbhh = (const float*)d_in[10];
    const float* linW = (const float*)d_in[11];  // [1,512]
    const float* linb = (const float*)d_in[12];
    float* dout = (float*)d_out;                 // [32,128,1]

    // workspace layout
    char* ws = (char*)d_ws;
    u16* enc  = (u16*)ws;                                  // 64 MB
    u16* rT   = (u16*)(ws + 67108864);                     // 512 KB
    u64* hb64 = (u64*)(ws + 67108864 + 524288);            // 512 KB tagged h

    init_misc<<<512, 256, 0, stream>>>(h0, rWhh, hb64, rT);
    enc_lstm<<<32, 512, 0, stream>>>(xseq, c0, Wih, Whh, bih, bhh, enc, hb64);
    dec_all<<<128, 512, 0, stream>>>(xseq + 512 * BATCH, enc, rT, rWih,
                                     rbih, rbhh, linW, linb, dout);
}

// Round 10
// 4989.766 us; speedup vs baseline: 1.0404x; 1.0404x over previous
//
#include <hip/hip_runtime.h>
#include <hip/hip_bf16.h>

typedef unsigned short u16;
typedef unsigned int u32;
typedef unsigned long long u64;

#define HD 512
#define BATCH 128
#define TENC 512
#define WPAD 520   // LDS row stride in bf16 elems (even -> u32-aligned rows)

typedef float f32x4 __attribute__((ext_vector_type(4)));
typedef short s16x8 __attribute__((ext_vector_type(8)));

__device__ __forceinline__ u16 f2b(float f) {
    u32 u = __float_as_uint(f);
    u32 r = (u + 0x7FFFu + ((u >> 16) & 1u)) >> 16;   // RNE
    return (u16)r;
}
__device__ __forceinline__ float b2f(u16 h) {
    return __uint_as_float(((u32)h) << 16);
}
__device__ __forceinline__ float sigm(float z) { return 1.0f / (1.0f + __expf(-z)); }
__device__ __forceinline__ float tanh_f(float z) { return 1.0f - 2.0f / (__expf(2.0f * z) + 1.0f); }

// ---------------------------------------------------------------------------
// init: seed tagged h-buffer. Layout: hb64[(g*2+parity)*4096 + b*256 + jp]
//   word = (bf16 h[2jp] | bf16 h[2jp+1]<<16) | ((u64)tag << 32)
// parity0 holds h_0 with tag 0; parity1 zeroed (tag 0, never matches t>=1).
// Also build rnn_Whh transposed bf16 [k][j] for coalesced decoder reads.
// ---------------------------------------------------------------------------
__global__ void init_misc(const float* __restrict__ h0, const float* __restrict__ rWhh,
                          u64* __restrict__ hb64, u16* __restrict__ rT) {
    int idx = blockIdx.x * 256 + threadIdx.x;      // 512 blocks x 256 = 131072
    if (idx < 65536) {                              // 8 g x 2 parity x 4096 words
        int g   = idx >> 13;
        int r   = idx & 8191;
        int p   = r >> 12;
        int ofs = r & 4095;
        int b   = ofs >> 8, jp = ofs & 255;
        u64 v = 0ull;                               // tag 0
        if (p == 0) {
            const float* hrow = h0 + (size_t)(g * 16 + b) * HD + jp * 2;
            u32 lo = (u32)f2b(hrow[0]) | ((u32)f2b(hrow[1]) << 16);
            v = (u64)lo;                            // tag 0 for h_0
        }
        hb64[(size_t)(g * 2 + p) * 4096 + b * 256 + jp] = v;
    }
    for (int i = idx; i < 262144; i += 131072) {    // rT[k*512+j] = rWhh[j][k]
        int k = i >> 9, j = i & 511;
        rT[i] = f2b(rWhh[j * 512 + k]);
    }
}

// ---------------------------------------------------------------------------
// Encoder LSTM: 8 batch-groups x 16 wgs -- EXACT round-6 proven kernel.
// Cross-wg h handoff via SELF-VALIDATING tagged 64-bit words: {bf16 pair,
// step tag} in one atomic dwordx2 agent-scope store. Readers poll the data
// words until tag==t. Parity-2 buffering.
// ---------------------------------------------------------------------------
__global__ __launch_bounds__(512, 2) void enc_lstm(
    const float* __restrict__ xseq, const float* __restrict__ c0,
    const float* __restrict__ Wih, const float* __restrict__ Whh,
    const float* __restrict__ bih, const float* __restrict__ bhh,
    u16* __restrict__ enc, u64* __restrict__ hb64) {

    __shared__ u16 hlds[16 * WPAD];     // 16640 B: staged h tile [16b][512k] bf16
    __shared__ float exg[16 * 132];     // 8448 B: gate pre-activations [b][128 rows]
    __shared__ float bias_l[128];
    __shared__ float wih_l[128];

    const int tid = threadIdx.x;
    const int g = blockIdx.x & 7;       // batch group
    const int sl = blockIdx.x >> 3;     // hidden slot 0..15

    if (tid < 128) {
        int n = (tid >> 5) * 512 + sl * 32 + (tid & 31);
        bias_l[tid] = bih[n] + bhh[n];
        wih_l[tid] = Wih[n];
    }

    const int bT = tid >> 5, jl = tid & 31;               // cell-update mapping
    float c = c0[(g * 16 + bT) * HD + sl * 32 + jl];      // persistent cell state

    const int lane = tid & 63, wv = tid >> 6;
    const int q = lane >> 4, cl = lane & 15;
    const int R = (wv >> 1) * 32 + (wv & 1) * 16;         // wave's 16 gate-rows

    // hoist this lane's 16 B-fragments of Whh into registers (64 VGPRs)
    s16x8 bw[16];
    {
        int r = R + cl;
        int grow = (r >> 5) * 512 + sl * 32 + (r & 31);
        const float* wrow = Whh + (size_t)grow * 512;
        #pragma unroll
        for (int ks = 0; ks < 16; ++ks) {
            s16x8 v;
            #pragma unroll
            for (int j = 0; j < 8; ++j)
                v[j] = (short)f2b(wrow[ks * 32 + q * 8 + j]);
            bw[ks] = v;
        }
    }

    u32* hlds32 = (u32*)hlds;
    __syncthreads();

    const int jgl = sl * 32 + jl;
    u64* dpl0 = hb64 + (size_t)(g * 2) * 4096 + bT * 256 + (jgl >> 1);
    u64* dpl1 = dpl0 + 4096;

    for (int t = 0; t < TENC; ++t) {
        // ---- stage h_t: poll tagged words of buf[t&1] until tag==t
        const u64* src = hb64 + (size_t)(g * 2 + (t & 1)) * 4096;
        const u32 want = (u32)t;
        u64 vv[8];
        #pragma unroll
        for (int i = 0; i < 8; ++i)
            vv[i] = __hip_atomic_load(src + tid + i * 512, __ATOMIC_RELAXED,
                                      __HIP_MEMORY_SCOPE_AGENT);
        float xv = xseq[t * BATCH + g * 16 + bT];   // prefetched; used post-MFMA
        for (;;) {
            bool ok = true;
            #pragma unroll
            for (int i = 0; i < 8; ++i) {
                if ((u32)(vv[i] >> 32) != want) {
                    ok = false;
                    vv[i] = __hip_atomic_load(src + tid + i * 512, __ATOMIC_RELAXED,
                                              __HIP_MEMORY_SCOPE_AGENT);
                }
            }
            if (ok) break;
        }
        #pragma unroll
        for (int i = 0; i < 8; ++i) {
            int idx = tid + i * 512;
            hlds32[(idx >> 8) * 260 + (idx & 255)] = (u32)vv[i];
        }
        __syncthreads();                            // S1: hlds ready

        // dual accumulators: halve the dependent MFMA chain
        f32x4 acc0 = {0.f, 0.f, 0.f, 0.f}, acc1 = {0.f, 0.f, 0.f, 0.f};
        #pragma unroll
        for (int ks = 0; ks < 16; ks += 2) {
            s16x8 av0 = *(const s16x8*)&hlds[cl * WPAD + ks * 32 + q * 8];
            s16x8 av1 = *(const s16x8*)&hlds[cl * WPAD + (ks + 1) * 32 + q * 8];
            acc0 = __builtin_amdgcn_mfma_f32_16x16x32_bf16(av0, bw[ks], acc0, 0, 0, 0);
            acc1 = __builtin_amdgcn_mfma_f32_16x16x32_bf16(av1, bw[ks + 1], acc1, 0, 0, 0);
        }
        f32x4 acc = acc0 + acc1;
        #pragma unroll
        for (int r4 = 0; r4 < 4; ++r4)
            exg[(q * 4 + r4) * 132 + R + cl] = acc[r4];   // D: row m=q*4+r4, col n=cl
        __syncthreads();                            // S2: exg ready + hlds reads done

        // LSTM cell for (bT, jl)
        const float* exb = &exg[bT * 132];
        float gi = exb[jl]      + xv * wih_l[jl]      + bias_l[jl];
        float gf = exb[32 + jl] + xv * wih_l[32 + jl] + bias_l[32 + jl];
        float gg = exb[64 + jl] + xv * wih_l[64 + jl] + bias_l[64 + jl];
        float go = exb[96 + jl] + xv * wih_l[96 + jl] + bias_l[96 + jl];
        c = sigm(gf) * c + sigm(gi) * tanh_f(gg);
        float hv = sigm(go) * tanh_f(c);
        u16 h16 = f2b(hv);

        // tagged h_{t+1} store: pair + tag in ONE atomic 8B store (critical path)
        u32 me = (u32)h16;
        u32 up = (u32)__shfl_down((int)me, 1, 64);
        if ((jl & 1) == 0) {
            u64 word = (u64)(me | (up << 16)) | ((u64)(u32)(t + 1) << 32);
            __hip_atomic_store(((t + 1) & 1) ? dpl1 : dpl0, word,
                               __ATOMIC_RELAXED, __HIP_MEMORY_SCOPE_AGENT);
        }
        // enc write AFTER the handoff store: off the critical path
        enc[((size_t)t * BATCH + g * 16 + bT) * HD + jgl] = h16;
    }
}

// ---------------------------------------------------------------------------
// Fused decoder: one wg per batch row, 32 steps. p2 3-DEEP rotating
// prefetch (A/B/C x 8 uint4 = 384B/lane in flight): A,B issued BEFORE p1
// (p1's ~1.7us covers the prologue RT), C after h8; steady state has 3
// iterations of compute covering each MALL round trip. Pure reordering of
// round-6-proven loads (same addresses, same bounds).
// ---------------------------------------------------------------------------
__global__ __launch_bounds__(512, 1) void dec_all(
    const float* __restrict__ xlast, const u16* __restrict__ enc,
    const u16* __restrict__ rT, const float* __restrict__ rWih,
    const float* __restrict__ rbih, const float* __restrict__ rbhh,
    const float* __restrict__ linW, const float* __restrict__ linb,
    float* __restrict__ dout) {

    __shared__ float hp[512];          // h entering the step
    __shared__ float ctxl[8 * 512];    // p1 partials, then p2 ctx partials
    __shared__ float red[512];         // hn broadcast, then reduce slots
    __shared__ float mw[8], lw[8];
    __shared__ float xsh;

    const int tid = threadIdx.x;
    const int b = blockIdx.x;
    const int wv = tid >> 6, lane = tid & 63;

    hp[tid] = b2f(enc[(size_t)511 * BATCH * HD + b * HD + tid]);  // h_enc
    float x = xlast[b];
    const float bia = rbih[tid] + rbhh[tid];
    const float wih = rWih[tid];
    const float lwt = linW[tid];
    const float lb = linb[0];
    const uint4* rT4 = (const uint4*)rT;                 // [512 k][64 chunks]
    const u16* ebase = enc + (size_t)b * HD + lane * 8;  // t-stride = 65536 elems
    __syncthreads();

    for (int s = 0; s < 32; ++s) {
        float m = -1e30f, l = 0.f;
        float acc[8] = {0, 0, 0, 0, 0, 0, 0, 0};
        float h8[8];
        uint4 bA[8], bB[8], bC[8];

        auto issue = [&](uint4* bf, int it) {
            #pragma unroll
            for (int i = 0; i < 8; ++i)
                bf[i] = *(const uint4*)(ebase +
                          (size_t)(it * 64 + i * 8 + wv) * 65536);
        };
        auto procit = [&](const uint4* bf) {
            float e[8][8], sp[8];
            #pragma unroll
            for (int i = 0; i < 8; ++i) {
                uint4 ev = bf[i];
                e[i][0] = b2f((u16)(ev.x & 0xFFFF)); e[i][1] = b2f((u16)(ev.x >> 16));
                e[i][2] = b2f((u16)(ev.y & 0xFFFF)); e[i][3] = b2f((u16)(ev.y >> 16));
                e[i][4] = b2f((u16)(ev.z & 0xFFFF)); e[i][5] = b2f((u16)(ev.z >> 16));
                e[i][6] = b2f((u16)(ev.w & 0xFFFF)); e[i][7] = b2f((u16)(ev.w >> 16));
                float sd = 0.f;
                #pragma unroll
                for (int j = 0; j < 8; ++j) sd = fmaf(e[i][j], h8[j], sd);
                sp[i] = sd;
            }
            // batched butterfly: 6 dependent stages, 8-way ILP
            #pragma unroll
            for (int mk = 1; mk < 64; mk <<= 1) {
                #pragma unroll
                for (int i = 0; i < 8; ++i) sp[i] += __shfl_xor(sp[i], mk, 64);
            }
            float pm = sp[0];
            #pragma unroll
            for (int i = 1; i < 8; ++i) pm = fmaxf(pm, sp[i]);
            if (pm > m) {                           // one rescale per 8-t block
                float sc = __expf(m - pm);
                l *= sc;
                #pragma unroll
                for (int j = 0; j < 8; ++j) acc[j] *= sc;
                m = pm;
            }
            #pragma unroll
            for (int i = 0; i < 8; ++i) {
                float p = __expf(sp[i] - m);
                l += p;
                #pragma unroll
                for (int j = 0; j < 8; ++j) acc[j] = fmaf(p, e[i][j], acc[j]);
            }
        };

        // prologue prefetch: its 0,1 in flight across all of p1
        issue(bA, 0);
        issue(bB, 1);

        // ---- phase 1: wave wv covers k in [wv*64, wv*64+64)
        float pa[8] = {0, 0, 0, 0, 0, 0, 0, 0};
        const uint4* base = rT4 + (size_t)(wv * 64) * 64 + lane;
        #pragma unroll 4
        for (int kk = 0; kk < 64; ++kk) {
            float hk = hp[wv * 64 + kk];
            uint4 w = base[kk * 64];
            pa[0] = fmaf(hk, b2f((u16)(w.x & 0xFFFF)), pa[0]);
            pa[1] = fmaf(hk, b2f((u16)(w.x >> 16)),    pa[1]);
            pa[2] = fmaf(hk, b2f((u16)(w.y & 0xFFFF)), pa[2]);
            pa[3] = fmaf(hk, b2f((u16)(w.y >> 16)),    pa[3]);
            pa[4] = fmaf(hk, b2f((u16)(w.z & 0xFFFF)), pa[4]);
            pa[5] = fmaf(hk, b2f((u16)(w.z >> 16)),    pa[5]);
            pa[6] = fmaf(hk, b2f((u16)(w.w & 0xFFFF)), pa[6]);
            pa[7] = fmaf(hk, b2f((u16)(w.w >> 16)),    pa[7]);
        }
        #pragma unroll
        for (int i = 0; i < 8; ++i) ctxl[wv * 512 + lane * 8 + i] = pa[i];
        __syncthreads();

        float a = bia + x * wih;
        #pragma unroll
        for (int i = 0; i < 8; ++i) a += ctxl[i * 512 + tid];
        float hv = tanh_f(a);
        red[tid] = hv;                  // hn broadcast
        __syncthreads();

        // ---- phase 2: wave wv handles t = it*64 + i*8 + wv, 3-deep pipeline
        #pragma unroll
        for (int i = 0; i < 8; ++i) h8[i] = red[lane * 8 + i];

        issue(bC, 2);
        procit(bA); issue(bA, 3);
        procit(bB); issue(bB, 4);
        procit(bC); issue(bC, 5);
        procit(bA); issue(bA, 6);
        procit(bB); issue(bB, 7);
        procit(bC);
        procit(bA);
        procit(bB);

        if (lane == 0) { mw[wv] = m; lw[wv] = l; }
        #pragma unroll
        for (int i = 0; i < 8; ++i) ctxl[wv * HD + lane * 8 + i] = acc[i];
        __syncthreads();

        // ---- phase 3: merge online-softmax states, project, relu
        float M = mw[0];
        #pragma unroll
        for (int i = 1; i < 8; ++i) M = fmaxf(M, mw[i]);
        float L = 0.f, aw[8];
        #pragma unroll
        for (int i = 0; i < 8; ++i) { aw[i] = __expf(mw[i] - M); L += aw[i] * lw[i]; }
        float cj = 0.f;
        #pragma unroll
        for (int i = 0; i < 8; ++i) cj = fmaf(aw[i], ctxl[i * HD + tid], cj);
        float r = cj * lwt;
        #pragma unroll
        for (int mk = 1; mk < 64; mk <<= 1) r += __shfl_xor(r, mk, 64);
        if (lane == 0) red[wv] = r;
        __syncthreads();
        if (tid == 0) {
            float o = (red[0] + red[1] + red[2] + red[3] +
                       red[4] + red[5] + red[6] + red[7]) / L + lb;
            o = fmaxf(o, 0.f);
            dout[s * BATCH + b] = o;
            xsh = o;
        }
        __syncthreads();
        x = xsh;
        hp[tid] = hv;                   // h for next step
        __syncthreads();
    }
}

// ---------------------------------------------------------------------------
extern "C" void kernel_launch(void* const* d_in, const int* in_sizes, int n_in,
                              void* d_out, int out_size, void* d_ws, size_t ws_size,
                              hipStream_t stream) {
    const float* xseq = (const float*)d_in[0];   // [513,128,1]
    const float* h0   = (const float*)d_in[1];
    const float* c0   = (const float*)d_in[2];
    const float* Wih  = (const float*)d_in[3];   // [2048,1]
    const float* Whh  = (const float*)d_in[4];   // [2048,512]
    const float* bih  = (const float*)d_in[5];
    const float* bhh  = (const float*)d_in[6];
    const float* rWih = (const float*)d_in[7];   // [512,1]
    const float* rWhh = (const float*)d_in[8];   // [512,512]
    const float* rbih = (const float*)d_in[9];
    const float* rbhh = (const float*)d_in[10];
    const float* linW = (const float*)d_in[11];  // [1,512]
    const float* linb = (const float*)d_in[12];
    float* dout = (float*)d_out;                 // [32,128,1]

    // workspace layout
    char* ws = (char*)d_ws;
    u16* enc  = (u16*)ws;                                  // 64 MB
    u16* rT   = (u16*)(ws + 67108864);                     // 512 KB
    u64* hb64 = (u64*)(ws + 67108864 + 524288);            // 512 KB tagged h

    init_misc<<<512, 256, 0, stream>>>(h0, rWhh, hb64, rT);
    enc_lstm<<<128, 512, 0, stream>>>(xseq, c0, Wih, Whh, bih, bhh, enc, hb64);
    dec_all<<<128, 512, 0, stream>>>(xseq + 512 * BATCH, enc, rT, rWih,
                                     rbih, rbhh, linW, linb, dout);
}